// Round 5
// baseline (238.330 us; speedup 1.0000x reference)
//
#include <hip/hip_runtime.h>
#include <math.h>

#define BATCH 8
#define CH    256
#define HWN   4096
#define DQK   16

typedef __attribute__((ext_vector_type(8))) short short8;
typedef __attribute__((ext_vector_type(4))) float float4v;

#define L2E 1.4426950408889634f

__device__ __forceinline__ unsigned short f2bf(float f) {
    union { float f; unsigned int u; } v; v.f = f;
    unsigned int r = v.u + 0x7FFF + ((v.u >> 16) & 1);   // RNE
    return (unsigned short)(r >> 16);
}
// HW packed f32->bf16 convert (RNE): %1 -> low16, %2 -> high16
__device__ __forceinline__ unsigned int cvtpk(float lo, float hi) {
    unsigned int r;
    asm("v_cvt_pk_bf16_f32 %0, %1, %2" : "=v"(r) : "v"(lo), "v"(hi));
    return r;
}
// 2^x via hardware v_exp_f32, compiler-managed TRANS hazards
__device__ __forceinline__ float ex2(float x) {
#if __has_builtin(__builtin_amdgcn_exp2f)
    return __builtin_amdgcn_exp2f(x);
#else
    return exp2f(x);
#endif
}
// ft row permutation: stored row s holds key m with s4=m2, s3=m4, s2=m3
// (bits 0,1,5+ unchanged). Makes S^T output registers align with PV B-frag
// slots in the SAME lane (no cross-lane transpose needed).
__device__ __forceinline__ int perm_ft(int m) {
    return (m & ~28) | ((m & 24) >> 1) | ((m & 4) << 2);
}

// ---------------- kernel 0: W_cat -> bf16, biases -> bcat ----------------
__global__ __launch_bounds__(256) void wcast_kernel(
    const float* __restrict__ Wf, const float* __restrict__ bf_,
    const float* __restrict__ Wg, const float* __restrict__ bg,
    const float* __restrict__ Wh, const float* __restrict__ bh,
    unsigned short* __restrict__ Wbf, float* __restrict__ bcat)
{
    const int r = blockIdx.x;   // 288 rows
    const int t = threadIdx.x;  // 256 cols
    const float* src = (r < 16) ? (Wf + r*CH) : (r < 32) ? (Wg + (r-16)*CH) : (Wh + (r-32)*CH);
    Wbf[r*CH + t] = f2bf(src[t]);
    if (t == 0) bcat[r] = (r < 16) ? bf_[r] : (r < 32) ? bg[r-16] : bh[r-32];
}

// ---------------- kernel 1: x[b][c][px] fp32 -> xt[b][px][c] bf16 ----------------
// float4 global loads (coalesced 256B/16 lanes), cvt_pk convert, dword LDS
// reads in phase 2 (pad 74 keeps rows 4B-aligned, ~2-way banks max).
__global__ __launch_bounds__(256) void xt_kernel(const float* __restrict__ x,
                                                 unsigned short* __restrict__ xt)
{
    const int t  = threadIdx.x;
    const int p0 = blockIdx.x * 64;
    const int c0 = blockIdx.y * 64;
    const int b  = blockIdx.z;
    __shared__ unsigned short tile[64][74];
    const int col4 = (t & 15) * 4;          // px base within tile
    const int cr   = t >> 4;                // 0..15
    #pragma unroll
    for (int j = 0; j < 4; j++) {
        int c = cr + j*16;
        float4 v = *(const float4*)&x[(size_t)(b*CH + c0 + c)*HWN + p0 + col4];
        unsigned int u01 = cvtpk(v.x, v.y), u23 = cvtpk(v.z, v.w);
        tile[col4+0][c] = (unsigned short)u01;
        tile[col4+1][c] = (unsigned short)(u01 >> 16);
        tile[col4+2][c] = (unsigned short)u23;
        tile[col4+3][c] = (unsigned short)(u23 >> 16);
    }
    __syncthreads();
    const int pr = t >> 2;
    const int cb = (t & 3) * 16;
    unsigned int outv[8];
    #pragma unroll
    for (int i = 0; i < 8; i++)
        outv[i] = *(const unsigned int*)&tile[pr][cb + 2*i];
    unsigned short* dst = &xt[(size_t)(b*HWN + p0 + pr)*CH + c0 + cb];
    *(uint4*)dst       = *(uint4*)&outv[0];
    *(uint4*)(dst + 8) = *(uint4*)&outv[4];
}

// ---------------- kernel 2: MFMA projection, rt-split x3 ----------------
// Grid (64 px-blocks, 8 b, 3 rt-groups of 6). C[288][4096] = Wbf @ bf16(x).
// A-frags direct from xt, B-frags direct from L2-hot Wbf. Group 0 holds
// ft (rt 0, perm_ft rows, PRE-SCALED by log2e for exp2 in attn) and g
// (rt 1); h rows -> h3 fragment layout.
__global__ __launch_bounds__(256, 6) void proj_kernel(
    const unsigned short* __restrict__ xt, const unsigned short* __restrict__ Wbf,
    const float* __restrict__ bcat,
    unsigned short* __restrict__ ft, unsigned short* __restrict__ g,
    unsigned short* __restrict__ h3)
{
    const int t      = threadIdx.x;
    const int px0    = blockIdx.x * 64;
    const int b      = blockIdx.y;
    const int rtbase = blockIdx.z * 6;
    const int lane = t & 63, w = t >> 6, l15 = lane & 15, quad = lane >> 4;

    float4v acc[6];
    #pragma unroll
    for (int rt = 0; rt < 6; rt++) acc[rt] = (float4v){0.f,0.f,0.f,0.f};

    const unsigned short* xrow = &xt[((size_t)(b*HWN + px0 + w*16 + l15))*CH + quad*8];
    const unsigned short* wrow = &Wbf[(size_t)l15*CH + quad*8];

    #pragma unroll
    for (int ks = 0; ks < 8; ks++) {
        short8 afrag = *(const short8*)&xrow[ks*32];
        #pragma unroll
        for (int rt = 0; rt < 6; rt++) {
            short8 bfrag = *(const short8*)&wrow[(size_t)(rtbase + rt)*16*CH + ks*32];
            acc[rt] = __builtin_amdgcn_mfma_f32_16x16x32_bf16(afrag, bfrag, acc[rt], 0, 0, 0);
        }
    }

    const int pxl = px0 + w*16 + quad*4;      // this lane's px base (+r)
    const int mt  = (px0 >> 5) + (w >> 1);
    const int sub = ((w & 1)*2 + (quad >> 1))*128 + l15*8 + (quad & 1)*4;
    #pragma unroll
    for (int rt = 0; rt < 6; rt++) {
        const int R = rtbase + rt;            // uniform
        if (R == 0) {                         // -> ft at perm_ft rows, * log2e
            float bv = bcat[l15];
            const int s0 = perm_ft(pxl);      // r only touches bits 0,1
            unsigned int p01 = cvtpk((acc[rt][0] + bv)*L2E, (acc[rt][1] + bv)*L2E);
            unsigned int p23 = cvtpk((acc[rt][2] + bv)*L2E, (acc[rt][3] + bv)*L2E);
            unsigned short* fp0 = &ft[((size_t)b*HWN + s0)*32];
            fp0[l15]       = (unsigned short)p01;         fp0[16 + l15]  = 0;
            fp0[32 + l15]  = (unsigned short)(p01 >> 16); fp0[48 + l15]  = 0;
            fp0[64 + l15]  = (unsigned short)p23;         fp0[80 + l15]  = 0;
            fp0[96 + l15]  = (unsigned short)(p23 >> 16); fp0[112 + l15] = 0;
        } else if (R == 1) {                  // -> g (4 consecutive px: uint2)
            float bv = bcat[16 + l15];
            unsigned int a01 = cvtpk(acc[rt][0] + bv, acc[rt][1] + bv);
            unsigned int a23 = cvtpk(acc[rt][2] + bv, acc[rt][3] + bv);
            *(uint2*)&g[(size_t)(b*DQK + l15)*HWN + pxl] = make_uint2(a01, a23);
        } else {                              // -> h3 frag layout
            float bv = bcat[R*16 + l15];
            unsigned int u0 = cvtpk(acc[rt][0] + bv, acc[rt][1] + bv);
            unsigned int u1 = cvtpk(acc[rt][2] + bv, acc[rt][3] + bv);
            *(uint2*)&h3[(((size_t)((b*128 + mt)*16 + (R-2))) << 9) + sub] = make_uint2(u0, u1);
        }
    }
}

// ---------------- kernel 3: MFMA flash attention, 4 waves / 32 q ----------------
// Block = 256 thr, (batch, 32-q tile), grid 1024 -> 4 blocks/CU (4
// independent barrier domains; R4 showed 2 blocks/CU can't fill the
// barrier bubbles: MfmaUtil 37 + VALU 29, rest idle). Wave w in 0..3:
// qt_w = w>>1 (q-tile), half = w&1 (32-key half). Per iter (64 keys):
// S^T 2 MFMA + 8 exp2 + pB b128 write -> barrier -> hr loads (single-buf,
// consumed after S^T window covers L2 latency) -> S^T(i+1) pipelined ->
// PV 16 MFMA (ctl 0..3 x qt 0..1 x grp 0..1) under setprio(1).
// Register budget ~108 (acc 32 + hr 32 + fr 16 + gfrag/P/addr) under the
// 128 cap of __launch_bounds__(256,4); R3 lesson: watch WRITE_SIZE for
// spill (must stay ~32.8 MB).
__global__ __launch_bounds__(256, 4) void attn_kernel(
    const unsigned short* __restrict__ ft, const unsigned short* __restrict__ g,
    const unsigned short* __restrict__ h3, const float* __restrict__ x,
    const float* __restrict__ gamma_p, float* __restrict__ out)
{
    const int t    = threadIdx.x;
    const int b    = blockIdx.x & 7;          // batch -> XCD pin
    const int q0   = (blockIdx.x >> 3) * 32;
    const int lane = t & 63, w = t >> 6, l15 = lane & 15, quad = lane >> 4;
    const int qt_w = w >> 1, half = w & 1;

    __shared__ __align__(16) uint4 pB[2][2][2][64];   // [buf][grp][qt][lane] 8 KB
    __shared__ float l_l[2][16][2];

    union { short8 v; unsigned short u[8]; } gfrag;   // B[k=quad*8+j][q=l15] of q-tile qt_w
    #pragma unroll
    for (int j = 0; j < 8; j++) {
        int k = quad*8 + j;
        gfrag.u[j] = (k < DQK) ? g[(size_t)(b*DQK + k)*HWN + q0 + qt_w*16 + l15] : (unsigned short)0;
    }

    const unsigned short* ftb = ft + (size_t)b*HWN*32;
    const unsigned short* h3b = h3 + ((size_t)b << 20);

    short8 fr[2][2];
    float4v acc[4][2];                        // [ctl][qt]
    #pragma unroll
    for (int i = 0; i < 4; i++)
        #pragma unroll
        for (int j = 0; j < 2; j++) acc[i][j] = (float4v){0.f,0.f,0.f,0.f};
    float l_acc = 0.f;
    uint4 P;

    // ---- prologue: fr tile0 -> slot0, S^T(0)+exp2 -> P, fr tile1 -> slot1 ----
    #pragma unroll
    for (int j = 0; j < 2; j++)
        fr[0][j] = *(const short8*)&ftb[(size_t)((half*2 + j)*16 + l15)*32 + quad*8];
    {
        float4v z = {0.f,0.f,0.f,0.f};
        float4v s0v = __builtin_amdgcn_mfma_f32_16x16x32_bf16(fr[0][0], gfrag.v, z, 0, 0, 0);
        float4v s1v = __builtin_amdgcn_mfma_f32_16x16x32_bf16(fr[0][1], gfrag.v, z, 0, 0, 0);
        float e0 = ex2(s0v[0]), e1 = ex2(s0v[1]), e2 = ex2(s0v[2]), e3 = ex2(s0v[3]);
        float e4 = ex2(s1v[0]), e5 = ex2(s1v[1]), e6 = ex2(s1v[2]), e7 = ex2(s1v[3]);
        l_acc += (e0 + e1) + (e2 + e3) + (e4 + e5) + (e6 + e7);
        P = make_uint4(cvtpk(e0, e1), cvtpk(e2, e3), cvtpk(e4, e5), cvtpk(e6, e7));
    }
    #pragma unroll
    for (int j = 0; j < 2; j++)
        fr[1][j] = *(const short8*)&ftb[(size_t)(64 + (half*2 + j)*16 + l15)*32 + quad*8];

    // Per-iter slots: S^T(i+1) reads fr[(i+1)&1]; prefetch fr tile i+2 ->
    // slot i&1. hr single-buffered: loaded right after barrier(i), consumed
    // in PV(i) after the S^T/exp window (~200 cyc L2 cover + 4-block TLP).
    // pB[i&1] WAR-safe: its last readers (iter i-2's PV) precede
    // barrier(i-1), which precedes this write.
#define ATTN_STEP(u, i, DO_NEXT) do {                                          \
    pB[u][half][qt_w][lane] = P;                                               \
    __syncthreads();                                                           \
    short8 hr[2][4];                                                           \
    _Pragma("unroll")                                                          \
    for (int grp = 0; grp < 2; grp++)                                          \
      _Pragma("unroll")                                                        \
      for (int ctl = 0; ctl < 4; ctl++)                                        \
        hr[grp][ctl] = *(const short8*)&h3b[(((size_t)((2*(i) + grp)*16 + w*4 + ctl)) << 9) + lane*8]; \
    if (DO_NEXT) {                                                             \
      const int nf = ((i) + 2) & 63;                                           \
      _Pragma("unroll")                                                        \
      for (int j = 0; j < 2; j++)                                              \
        fr[u][j] = *(const short8*)&ftb[(size_t)(nf*64 + (half*2 + j)*16 + l15)*32 + quad*8]; \
      float4v z = {0.f,0.f,0.f,0.f};                                           \
      float4v s0v = __builtin_amdgcn_mfma_f32_16x16x32_bf16(fr[(u)^1][0], gfrag.v, z, 0, 0, 0); \
      float4v s1v = __builtin_amdgcn_mfma_f32_16x16x32_bf16(fr[(u)^1][1], gfrag.v, z, 0, 0, 0); \
      float e0 = ex2(s0v[0]), e1 = ex2(s0v[1]), e2 = ex2(s0v[2]), e3 = ex2(s0v[3]); \
      float e4 = ex2(s1v[0]), e5 = ex2(s1v[1]), e6 = ex2(s1v[2]), e7 = ex2(s1v[3]); \
      l_acc += (e0 + e1) + (e2 + e3) + (e4 + e5) + (e6 + e7);                  \
      P = make_uint4(cvtpk(e0, e1), cvtpk(e2, e3), cvtpk(e4, e5), cvtpk(e6, e7)); \
    }                                                                          \
    __builtin_amdgcn_s_setprio(1);                                             \
    _Pragma("unroll")                                                          \
    for (int grp = 0; grp < 2; grp++) {                                        \
      _Pragma("unroll")                                                        \
      for (int qt = 0; qt < 2; qt++) {                                         \
        union { uint4 uu; short8 v; } bq;                                      \
        bq.uu = pB[u][grp][qt][lane];                                          \
        _Pragma("unroll")                                                      \
        for (int ctl = 0; ctl < 4; ctl++)                                      \
          acc[ctl][qt] = __builtin_amdgcn_mfma_f32_16x16x32_bf16(hr[grp][ctl], bq.v, acc[ctl][qt], 0, 0, 0); \
      }                                                                        \
    }                                                                          \
    __builtin_amdgcn_s_setprio(0);                                             \
  } while (0)

    for (int i0 = 0; i0 < 62; i0 += 2) {
        ATTN_STEP(0, i0, 1);
        ATTN_STEP(1, i0 + 1, 1);
    }
    ATTN_STEP(0, 62, 1);   // computes S^T(63)+P; fr prefetch wraps (dead)
    ATTN_STEP(1, 63, 0);   // peeled tail: write P(63), PV(63) only
#undef ATTN_STEP

    // ---- l: reduce over quads; combine halves via LDS ----
    l_acc += __shfl_xor(l_acc, 16, 64);
    l_acc += __shfl_xor(l_acc, 32, 64);
    if (quad == 0) l_l[qt_w][l15][half] = l_acc;
    __syncthreads();

    const float gamma = *gamma_p;
    float linv[2];
    #pragma unroll
    for (int qt = 0; qt < 2; qt++) linv[qt] = 1.f / (l_l[qt][l15][0] + l_l[qt][l15][1]);
    #pragma unroll
    for (int ctl = 0; ctl < 4; ctl++) {
        #pragma unroll
        for (int r = 0; r < 4; r++) {
            int c = w*64 + ctl*16 + quad*4 + r;
            size_t base = (size_t)(b*CH + c)*HWN + q0;
            #pragma unroll
            for (int qt = 0; qt < 2; qt++) {
                size_t o = base + qt*16 + l15;
                out[o] = gamma * acc[ctl][qt][r] * linv[qt] + x[o];
            }
        }
    }
}

extern "C" void kernel_launch(void* const* d_in, const int* in_sizes, int n_in,
                              void* d_out, int out_size, void* d_ws, size_t ws_size,
                              hipStream_t stream) {
    const float* x     = (const float*)d_in[0];
    const float* Wf    = (const float*)d_in[1];
    const float* bf_   = (const float*)d_in[2];
    const float* Wg    = (const float*)d_in[3];
    const float* bg    = (const float*)d_in[4];
    const float* Wh    = (const float*)d_in[5];
    const float* bh    = (const float*)d_in[6];
    const float* gamma = (const float*)d_in[7];
    float* out = (float*)d_out;

    // ws: xt 16.8MB | ft 2MB | g 1MB | h3 16.8MB | Wbf 147KB | bcat
    unsigned short* xt   = (unsigned short*)d_ws;
    unsigned short* ftp  = xt  + (size_t)BATCH*HWN*CH;
    unsigned short* g    = ftp + (size_t)BATCH*HWN*32;
    unsigned short* h3   = g   + (size_t)BATCH*DQK*HWN;
    unsigned short* Wbf  = h3  + (size_t)BATCH*128*16*512;
    float*          bcat = (float*)(Wbf + 288*CH);

    wcast_kernel<<<dim3(288), 256, 0, stream>>>(Wf, bf_, Wg, bg, Wh, bh, Wbf, bcat);
    xt_kernel<<<dim3(HWN/64, CH/64, BATCH), 256, 0, stream>>>(x, xt);
    proj_kernel<<<dim3(HWN/64, BATCH, 3), 256, 0, stream>>>(xt, Wbf, bcat, ftp, g, h3);
    attn_kernel<<<dim3((HWN/32)*BATCH), 256, 0, stream>>>(ftp, g, h3, x, gamma, out);
}

// Round 6
// 235.682 us; speedup vs baseline: 1.0112x; 1.0112x over previous
//
#include <hip/hip_runtime.h>
#include <math.h>

#define BATCH 8
#define CH    256
#define HWN   4096
#define DQK   16

typedef __attribute__((ext_vector_type(8))) short short8;
typedef __attribute__((ext_vector_type(4))) float float4v;

#define L2E 1.4426950408889634f

__device__ __forceinline__ unsigned short f2bf(float f) {
    union { float f; unsigned int u; } v; v.f = f;
    unsigned int r = v.u + 0x7FFF + ((v.u >> 16) & 1);   // RNE
    return (unsigned short)(r >> 16);
}
// HW packed f32->bf16 convert (RNE): %1 -> low16, %2 -> high16
__device__ __forceinline__ unsigned int cvtpk(float lo, float hi) {
    unsigned int r;
    asm("v_cvt_pk_bf16_f32 %0, %1, %2" : "=v"(r) : "v"(lo), "v"(hi));
    return r;
}
// 2^x via hardware v_exp_f32, compiler-managed TRANS hazards
__device__ __forceinline__ float ex2(float x) {
#if __has_builtin(__builtin_amdgcn_exp2f)
    return __builtin_amdgcn_exp2f(x);
#else
    return exp2f(x);
#endif
}
// Block barrier WITHOUT the vmcnt(0) drain __syncthreads carries (T4):
// only LDS ordering is required for the pB exchange; global prefetches
// stay in flight across the barrier.
__device__ __forceinline__ void lds_barrier() {
    asm volatile("s_waitcnt lgkmcnt(0)" ::: "memory");
    __builtin_amdgcn_s_barrier();
}
// ft row permutation: stored row s holds key m with s4=m2, s3=m4, s2=m3
// (bits 0,1,5+ unchanged). Makes S^T output registers align with PV B-frag
// slots in the SAME lane (no cross-lane transpose needed).
__device__ __forceinline__ int perm_ft(int m) {
    return (m & ~28) | ((m & 24) >> 1) | ((m & 4) << 2);
}

// ---------------- kernel 0: W_cat -> bf16, biases -> bcat ----------------
__global__ __launch_bounds__(256) void wcast_kernel(
    const float* __restrict__ Wf, const float* __restrict__ bf_,
    const float* __restrict__ Wg, const float* __restrict__ bg,
    const float* __restrict__ Wh, const float* __restrict__ bh,
    unsigned short* __restrict__ Wbf, float* __restrict__ bcat)
{
    const int r = blockIdx.x;   // 288 rows
    const int t = threadIdx.x;  // 256 cols
    const float* src = (r < 16) ? (Wf + r*CH) : (r < 32) ? (Wg + (r-16)*CH) : (Wh + (r-32)*CH);
    Wbf[r*CH + t] = f2bf(src[t]);
    if (t == 0) bcat[r] = (r < 16) ? bf_[r] : (r < 32) ? bg[r-16] : bh[r-32];
}

// ---------------- kernel 1: x[b][c][px] fp32 -> xt[b][px][c] bf16 ----------------
// float4 global loads (coalesced 256B/16 lanes), cvt_pk convert, dword LDS
// reads in phase 2 (pad 74 keeps rows 4B-aligned, ~2-way banks max).
__global__ __launch_bounds__(256) void xt_kernel(const float* __restrict__ x,
                                                 unsigned short* __restrict__ xt)
{
    const int t  = threadIdx.x;
    const int p0 = blockIdx.x * 64;
    const int c0 = blockIdx.y * 64;
    const int b  = blockIdx.z;
    __shared__ unsigned short tile[64][74];
    const int col4 = (t & 15) * 4;          // px base within tile
    const int cr   = t >> 4;                // 0..15
    #pragma unroll
    for (int j = 0; j < 4; j++) {
        int c = cr + j*16;
        float4 v = *(const float4*)&x[(size_t)(b*CH + c0 + c)*HWN + p0 + col4];
        unsigned int u01 = cvtpk(v.x, v.y), u23 = cvtpk(v.z, v.w);
        tile[col4+0][c] = (unsigned short)u01;
        tile[col4+1][c] = (unsigned short)(u01 >> 16);
        tile[col4+2][c] = (unsigned short)u23;
        tile[col4+3][c] = (unsigned short)(u23 >> 16);
    }
    __syncthreads();
    const int pr = t >> 2;
    const int cb = (t & 3) * 16;
    unsigned int outv[8];
    #pragma unroll
    for (int i = 0; i < 8; i++)
        outv[i] = *(const unsigned int*)&tile[pr][cb + 2*i];
    unsigned short* dst = &xt[(size_t)(b*HWN + p0 + pr)*CH + c0 + cb];
    *(uint4*)dst       = *(uint4*)&outv[0];
    *(uint4*)(dst + 8) = *(uint4*)&outv[4];
}

// ---------------- kernel 2: MFMA projection, rt-split x3 ----------------
// Grid (64 px-blocks, 8 b, 3 rt-groups of 6). C[288][4096] = Wbf @ bf16(x).
// A-frags direct from xt, B-frags direct from L2-hot Wbf. Group 0 holds
// ft (rt 0, perm_ft rows, PRE-SCALED by log2e for exp2 in attn) and g
// (rt 1); h rows -> h3 fragment layout.
__global__ __launch_bounds__(256, 6) void proj_kernel(
    const unsigned short* __restrict__ xt, const unsigned short* __restrict__ Wbf,
    const float* __restrict__ bcat,
    unsigned short* __restrict__ ft, unsigned short* __restrict__ g,
    unsigned short* __restrict__ h3)
{
    const int t      = threadIdx.x;
    const int px0    = blockIdx.x * 64;
    const int b      = blockIdx.y;
    const int rtbase = blockIdx.z * 6;
    const int lane = t & 63, w = t >> 6, l15 = lane & 15, quad = lane >> 4;

    float4v acc[6];
    #pragma unroll
    for (int rt = 0; rt < 6; rt++) acc[rt] = (float4v){0.f,0.f,0.f,0.f};

    const unsigned short* xrow = &xt[((size_t)(b*HWN + px0 + w*16 + l15))*CH + quad*8];
    const unsigned short* wrow = &Wbf[(size_t)l15*CH + quad*8];

    #pragma unroll
    for (int ks = 0; ks < 8; ks++) {
        short8 afrag = *(const short8*)&xrow[ks*32];
        #pragma unroll
        for (int rt = 0; rt < 6; rt++) {
            short8 bfrag = *(const short8*)&wrow[(size_t)(rtbase + rt)*16*CH + ks*32];
            acc[rt] = __builtin_amdgcn_mfma_f32_16x16x32_bf16(afrag, bfrag, acc[rt], 0, 0, 0);
        }
    }

    const int pxl = px0 + w*16 + quad*4;      // this lane's px base (+r)
    const int mt  = (px0 >> 5) + (w >> 1);
    const int sub = ((w & 1)*2 + (quad >> 1))*128 + l15*8 + (quad & 1)*4;
    #pragma unroll
    for (int rt = 0; rt < 6; rt++) {
        const int R = rtbase + rt;            // uniform
        if (R == 0) {                         // -> ft at perm_ft rows, * log2e
            float bv = bcat[l15];
            const int s0 = perm_ft(pxl);      // r only touches bits 0,1
            unsigned int p01 = cvtpk((acc[rt][0] + bv)*L2E, (acc[rt][1] + bv)*L2E);
            unsigned int p23 = cvtpk((acc[rt][2] + bv)*L2E, (acc[rt][3] + bv)*L2E);
            unsigned short* fp0 = &ft[((size_t)b*HWN + s0)*32];
            fp0[l15]       = (unsigned short)p01;         fp0[16 + l15]  = 0;
            fp0[32 + l15]  = (unsigned short)(p01 >> 16); fp0[48 + l15]  = 0;
            fp0[64 + l15]  = (unsigned short)p23;         fp0[80 + l15]  = 0;
            fp0[96 + l15]  = (unsigned short)(p23 >> 16); fp0[112 + l15] = 0;
        } else if (R == 1) {                  // -> g (4 consecutive px: uint2)
            float bv = bcat[16 + l15];
            unsigned int a01 = cvtpk(acc[rt][0] + bv, acc[rt][1] + bv);
            unsigned int a23 = cvtpk(acc[rt][2] + bv, acc[rt][3] + bv);
            *(uint2*)&g[(size_t)(b*DQK + l15)*HWN + pxl] = make_uint2(a01, a23);
        } else {                              // -> h3 frag layout
            float bv = bcat[R*16 + l15];
            unsigned int u0 = cvtpk(acc[rt][0] + bv, acc[rt][1] + bv);
            unsigned int u1 = cvtpk(acc[rt][2] + bv, acc[rt][3] + bv);
            *(uint2*)&h3[(((size_t)((b*128 + mt)*16 + (R-2))) << 9) + sub] = make_uint2(u0, u1);
        }
    }
}

// ---------------- kernel 3: MFMA flash attention, 8 waves ----------------
// Block = 512 thr, (batch, 64-q tile), grid 512 (R5 lesson: 32-q blocks
// halve arithmetic intensity vs the ft/h3 streams -> regression; stay 64q).
// Producer role (S^T): wave -> (qt_w = w>>1, half = w&1), unchanged.
// Consumer role (PV): wave owns 64c x 32q (qh = w>>2, cs = w&3) -> B-frag
// reused across 4 c-tiles: 4 pB ds_read_b128/iter instead of 8 (LDS BW was
// a co-limiter: 144 KB/CU-iter ~ MFMA time). hr (8 loads, L2-hot h3) issued
// BEFORE the barrier they cross; in-loop barrier is lgkmcnt-only (T4 - no
// vmcnt drain), so they stay in flight through it and land during S^T.
// R3 lesson: watch WRITE_SIZE ~32.8 MB for spill (budget ~110 VGPR < 128).
__global__ __launch_bounds__(512, 4) void attn_kernel(
    const unsigned short* __restrict__ ft, const unsigned short* __restrict__ g,
    const unsigned short* __restrict__ h3, const float* __restrict__ x,
    const float* __restrict__ gamma_p, float* __restrict__ out)
{
    const int t    = threadIdx.x;
    const int b    = blockIdx.x & 7;          // batch -> XCD pin
    const int q0   = (blockIdx.x >> 3) * 64;
    const int lane = t & 63, w = t >> 6, l15 = lane & 15, quad = lane >> 4;
    const int qt_w = w >> 1, half = w & 1;    // producer (S^T) role
    const int qh2  = (w >> 2) * 2;            // consumer q-tile base (0 or 2)
    const int cs4  = (w & 3) * 4;             // consumer c-subtile base (0,4,8,12)

    __shared__ __align__(16) uint4 pB[2][2][4][64];   // [buf][half][qt][lane] 16 KB
    __shared__ float l_l[4][16][2];

    union { short8 v; unsigned short u[8]; } gfrag;   // B[k=quad*8+j][q=l15] of q-tile qt_w
    #pragma unroll
    for (int j = 0; j < 8; j++) {
        int k = quad*8 + j;
        gfrag.u[j] = (k < DQK) ? g[(size_t)(b*DQK + k)*HWN + q0 + qt_w*16 + l15] : (unsigned short)0;
    }

    const unsigned short* ftb = ft + (size_t)b*HWN*32;
    const unsigned short* h3b = h3 + ((size_t)b << 20);

    short8 fr[2][2];
    float4v acc[4][2];                        // [ctl (c-tile)][j (q-tile)]
    #pragma unroll
    for (int i = 0; i < 4; i++)
        #pragma unroll
        for (int j = 0; j < 2; j++) acc[i][j] = (float4v){0.f,0.f,0.f,0.f};
    float l_acc = 0.f;
    uint4 P;

    // ---- prologue: fr tile0 -> slot0, S^T(0)+exp2 -> P, fr tile1 -> slot1 ----
    #pragma unroll
    for (int j = 0; j < 2; j++)
        fr[0][j] = *(const short8*)&ftb[(size_t)((half*2 + j)*16 + l15)*32 + quad*8];
    {
        float4v z = {0.f,0.f,0.f,0.f};
        float4v s0v = __builtin_amdgcn_mfma_f32_16x16x32_bf16(fr[0][0], gfrag.v, z, 0, 0, 0);
        float4v s1v = __builtin_amdgcn_mfma_f32_16x16x32_bf16(fr[0][1], gfrag.v, z, 0, 0, 0);
        float e0 = ex2(s0v[0]), e1 = ex2(s0v[1]), e2 = ex2(s0v[2]), e3 = ex2(s0v[3]);
        float e4 = ex2(s1v[0]), e5 = ex2(s1v[1]), e6 = ex2(s1v[2]), e7 = ex2(s1v[3]);
        l_acc += (e0 + e1) + (e2 + e3) + (e4 + e5) + (e6 + e7);
        P = make_uint4(cvtpk(e0, e1), cvtpk(e2, e3), cvtpk(e4, e5), cvtpk(e6, e7));
    }
    #pragma unroll
    for (int j = 0; j < 2; j++)
        fr[1][j] = *(const short8*)&ftb[(size_t)(64 + (half*2 + j)*16 + l15)*32 + quad*8];

    // Per-iter: hr loads (tile i, pre-barrier, span it) -> pB write ->
    // lgkm-barrier -> fr prefetch (i+2, no wrap: dead-slop reads stay in ws)
    // + S^T(i+1)+exp2 -> P -> PV(i) under setprio. pB[u] WAR-safe: readers
    // at iter i-2 consumed pre-barrier(i-1); write is post-barrier(i-1).
#define ATTN_STEP(u, i, DO_NEXT) do {                                          \
    short8 hr[2][4];                                                           \
    _Pragma("unroll")                                                          \
    for (int grp = 0; grp < 2; grp++)                                          \
      _Pragma("unroll")                                                        \
      for (int ctl = 0; ctl < 4; ctl++)                                        \
        hr[grp][ctl] = *(const short8*)&h3b[(((size_t)((2*(i) + grp)*16 + cs4 + ctl)) << 9) + lane*8]; \
    pB[u][half][qt_w][lane] = P;                                               \
    lds_barrier();                                                             \
    if (DO_NEXT) {                                                             \
      const int nf = (i) + 2;                                                  \
      _Pragma("unroll")                                                        \
      for (int j = 0; j < 2; j++)                                              \
        fr[u][j] = *(const short8*)&ftb[(size_t)(nf*64 + (half*2 + j)*16 + l15)*32 + quad*8]; \
      float4v z = {0.f,0.f,0.f,0.f};                                           \
      float4v s0v = __builtin_amdgcn_mfma_f32_16x16x32_bf16(fr[(u)^1][0], gfrag.v, z, 0, 0, 0); \
      float4v s1v = __builtin_amdgcn_mfma_f32_16x16x32_bf16(fr[(u)^1][1], gfrag.v, z, 0, 0, 0); \
      float e0 = ex2(s0v[0]), e1 = ex2(s0v[1]), e2 = ex2(s0v[2]), e3 = ex2(s0v[3]); \
      float e4 = ex2(s1v[0]), e5 = ex2(s1v[1]), e6 = ex2(s1v[2]), e7 = ex2(s1v[3]); \
      l_acc += (e0 + e1) + (e2 + e3) + (e4 + e5) + (e6 + e7);                  \
      P = make_uint4(cvtpk(e0, e1), cvtpk(e2, e3), cvtpk(e4, e5), cvtpk(e6, e7)); \
    }                                                                          \
    __builtin_amdgcn_s_setprio(1);                                             \
    _Pragma("unroll")                                                          \
    for (int grp = 0; grp < 2; grp++) {                                        \
      union { uint4 uu; short8 v; } bq0, bq1;                                  \
      bq0.uu = pB[u][grp][qh2 + 0][lane];                                      \
      bq1.uu = pB[u][grp][qh2 + 1][lane];                                      \
      _Pragma("unroll")                                                        \
      for (int ctl = 0; ctl < 4; ctl++) {                                      \
        acc[ctl][0] = __builtin_amdgcn_mfma_f32_16x16x32_bf16(hr[grp][ctl], bq0.v, acc[ctl][0], 0, 0, 0); \
        acc[ctl][1] = __builtin_amdgcn_mfma_f32_16x16x32_bf16(hr[grp][ctl], bq1.v, acc[ctl][1], 0, 0, 0); \
      }                                                                        \
    }                                                                          \
    __builtin_amdgcn_s_setprio(0);                                             \
  } while (0)

    for (int i0 = 0; i0 < 62; i0 += 2) {
        ATTN_STEP(0, i0, 1);
        ATTN_STEP(1, i0 + 1, 1);
    }
    ATTN_STEP(0, 62, 1);   // computes S^T(63)+P; fr prefetch (tile 64/65) is dead slop
    ATTN_STEP(1, 63, 0);   // peeled tail: write P(63), PV(63) only
#undef ATTN_STEP

    // ---- l: reduce over quads; combine halves via LDS ----
    l_acc += __shfl_xor(l_acc, 16, 64);
    l_acc += __shfl_xor(l_acc, 32, 64);
    if (quad == 0) l_l[qt_w][l15][half] = l_acc;
    __syncthreads();

    const float gamma = *gamma_p;
    float linv[2];
    #pragma unroll
    for (int j = 0; j < 2; j++) linv[j] = 1.f / (l_l[qh2 + j][l15][0] + l_l[qh2 + j][l15][1]);
    #pragma unroll
    for (int ctl = 0; ctl < 4; ctl++) {
        #pragma unroll
        for (int r = 0; r < 4; r++) {
            int c = cs4*16 + ctl*16 + quad*4 + r;
            size_t base = (size_t)(b*CH + c)*HWN + q0 + (qh2 >> 1)*32;
            #pragma unroll
            for (int j = 0; j < 2; j++) {
                size_t o = base + j*16 + l15;
                out[o] = gamma * acc[ctl][j][r] * linv[j] + x[o];
            }
        }
    }
}

extern "C" void kernel_launch(void* const* d_in, const int* in_sizes, int n_in,
                              void* d_out, int out_size, void* d_ws, size_t ws_size,
                              hipStream_t stream) {
    const float* x     = (const float*)d_in[0];
    const float* Wf    = (const float*)d_in[1];
    const float* bf_   = (const float*)d_in[2];
    const float* Wg    = (const float*)d_in[3];
    const float* bg    = (const float*)d_in[4];
    const float* Wh    = (const float*)d_in[5];
    const float* bh    = (const float*)d_in[6];
    const float* gamma = (const float*)d_in[7];
    float* out = (float*)d_out;

    // ws: xt 16.8MB | ft 2MB | g 1MB | h3 16.8MB | Wbf 147KB | bcat
    unsigned short* xt   = (unsigned short*)d_ws;
    unsigned short* ftp  = xt  + (size_t)BATCH*HWN*CH;
    unsigned short* g    = ftp + (size_t)BATCH*HWN*32;
    unsigned short* h3   = g   + (size_t)BATCH*DQK*HWN;
    unsigned short* Wbf  = h3  + (size_t)BATCH*128*16*512;
    float*          bcat = (float*)(Wbf + 288*CH);

    wcast_kernel<<<dim3(288), 256, 0, stream>>>(Wf, bf_, Wg, bg, Wh, bh, Wbf, bcat);
    xt_kernel<<<dim3(HWN/64, CH/64, BATCH), 256, 0, stream>>>(x, xt);
    proj_kernel<<<dim3(HWN/64, BATCH, 3), 256, 0, stream>>>(xt, Wbf, bcat, ftp, g, h3);
    attn_kernel<<<dim3((HWN/64)*BATCH), 512, 0, stream>>>(ftp, g, h3, x, gamma, out);
}

// Round 7
// 215.320 us; speedup vs baseline: 1.1069x; 1.0946x over previous
//
#include <hip/hip_runtime.h>
#include <math.h>

#define BATCH 8
#define CH    256
#define HWN   4096
#define DQK   16

typedef __attribute__((ext_vector_type(8))) short short8;
typedef __attribute__((ext_vector_type(4))) float float4v;

#define L2E 1.4426950408889634f

__device__ __forceinline__ unsigned short f2bf(float f) {
    union { float f; unsigned int u; } v; v.f = f;
    unsigned int r = v.u + 0x7FFF + ((v.u >> 16) & 1);   // RNE
    return (unsigned short)(r >> 16);
}
// HW packed f32->bf16 convert (RNE): %1 -> low16, %2 -> high16
__device__ __forceinline__ unsigned int cvtpk(float lo, float hi) {
    unsigned int r;
    asm("v_cvt_pk_bf16_f32 %0, %1, %2" : "=v"(r) : "v"(lo), "v"(hi));
    return r;
}
// 2^x via hardware v_exp_f32, compiler-managed TRANS hazards
__device__ __forceinline__ float ex2(float x) {
#if __has_builtin(__builtin_amdgcn_exp2f)
    return __builtin_amdgcn_exp2f(x);
#else
    return exp2f(x);
#endif
}
// Block barrier WITHOUT the vmcnt(0) drain __syncthreads carries (T4):
// only LDS ordering is required for the pB exchange; global prefetches
// stay in flight across the barrier.
__device__ __forceinline__ void lds_barrier() {
    asm volatile("s_waitcnt lgkmcnt(0)" ::: "memory");
    __builtin_amdgcn_s_barrier();
}
// ft row permutation: stored row s holds key m with s4=m2, s3=m4, s2=m3
// (bits 0,1,5+ unchanged). Makes S^T output registers align with PV B-frag
// slots in the SAME lane (no cross-lane transpose needed).
__device__ __forceinline__ int perm_ft(int m) {
    return (m & ~28) | ((m & 24) >> 1) | ((m & 4) << 2);
}

// ---------------- kernel 0: W_cat -> bf16, biases -> bcat ----------------
__global__ __launch_bounds__(256) void wcast_kernel(
    const float* __restrict__ Wf, const float* __restrict__ bf_,
    const float* __restrict__ Wg, const float* __restrict__ bg,
    const float* __restrict__ Wh, const float* __restrict__ bh,
    unsigned short* __restrict__ Wbf, float* __restrict__ bcat)
{
    const int r = blockIdx.x;   // 288 rows
    const int t = threadIdx.x;  // 256 cols
    const float* src = (r < 16) ? (Wf + r*CH) : (r < 32) ? (Wg + (r-16)*CH) : (Wh + (r-32)*CH);
    Wbf[r*CH + t] = f2bf(src[t]);
    if (t == 0) bcat[r] = (r < 16) ? bf_[r] : (r < 32) ? bg[r-16] : bh[r-32];
}

// ---------------- kernel 1: x[b][c][px] fp32 -> xt[b][px][c] bf16 ----------------
// float4 global loads (coalesced 256B/16 lanes), cvt_pk convert, dword LDS
// reads in phase 2 (pad 74 keeps rows 4B-aligned, ~2-way banks max).
__global__ __launch_bounds__(256) void xt_kernel(const float* __restrict__ x,
                                                 unsigned short* __restrict__ xt)
{
    const int t  = threadIdx.x;
    const int p0 = blockIdx.x * 64;
    const int c0 = blockIdx.y * 64;
    const int b  = blockIdx.z;
    __shared__ unsigned short tile[64][74];
    const int col4 = (t & 15) * 4;          // px base within tile
    const int cr   = t >> 4;                // 0..15
    #pragma unroll
    for (int j = 0; j < 4; j++) {
        int c = cr + j*16;
        float4 v = *(const float4*)&x[(size_t)(b*CH + c0 + c)*HWN + p0 + col4];
        unsigned int u01 = cvtpk(v.x, v.y), u23 = cvtpk(v.z, v.w);
        tile[col4+0][c] = (unsigned short)u01;
        tile[col4+1][c] = (unsigned short)(u01 >> 16);
        tile[col4+2][c] = (unsigned short)u23;
        tile[col4+3][c] = (unsigned short)(u23 >> 16);
    }
    __syncthreads();
    const int pr = t >> 2;
    const int cb = (t & 3) * 16;
    unsigned int outv[8];
    #pragma unroll
    for (int i = 0; i < 8; i++)
        outv[i] = *(const unsigned int*)&tile[pr][cb + 2*i];
    unsigned short* dst = &xt[(size_t)(b*HWN + p0 + pr)*CH + c0 + cb];
    *(uint4*)dst       = *(uint4*)&outv[0];
    *(uint4*)(dst + 8) = *(uint4*)&outv[4];
}

// ---------------- kernel 2: MFMA projection, rt-split x3 ----------------
// Grid (64 px-blocks, 8 b, 3 rt-groups of 6). C[288][4096] = Wbf @ bf16(x).
// A-frags direct from xt, B-frags direct from L2-hot Wbf. Group 0 holds
// ft (rt 0, perm_ft rows, PRE-SCALED by log2e for exp2 in attn) and g
// (rt 1); h rows -> h3 fragment layout.
__global__ __launch_bounds__(256, 6) void proj_kernel(
    const unsigned short* __restrict__ xt, const unsigned short* __restrict__ Wbf,
    const float* __restrict__ bcat,
    unsigned short* __restrict__ ft, unsigned short* __restrict__ g,
    unsigned short* __restrict__ h3)
{
    const int t      = threadIdx.x;
    const int px0    = blockIdx.x * 64;
    const int b      = blockIdx.y;
    const int rtbase = blockIdx.z * 6;
    const int lane = t & 63, w = t >> 6, l15 = lane & 15, quad = lane >> 4;

    float4v acc[6];
    #pragma unroll
    for (int rt = 0; rt < 6; rt++) acc[rt] = (float4v){0.f,0.f,0.f,0.f};

    const unsigned short* xrow = &xt[((size_t)(b*HWN + px0 + w*16 + l15))*CH + quad*8];
    const unsigned short* wrow = &Wbf[(size_t)l15*CH + quad*8];

    #pragma unroll
    for (int ks = 0; ks < 8; ks++) {
        short8 afrag = *(const short8*)&xrow[ks*32];
        #pragma unroll
        for (int rt = 0; rt < 6; rt++) {
            short8 bfrag = *(const short8*)&wrow[(size_t)(rtbase + rt)*16*CH + ks*32];
            acc[rt] = __builtin_amdgcn_mfma_f32_16x16x32_bf16(afrag, bfrag, acc[rt], 0, 0, 0);
        }
    }

    const int pxl = px0 + w*16 + quad*4;      // this lane's px base (+r)
    const int mt  = (px0 >> 5) + (w >> 1);
    const int sub = ((w & 1)*2 + (quad >> 1))*128 + l15*8 + (quad & 1)*4;
    #pragma unroll
    for (int rt = 0; rt < 6; rt++) {
        const int R = rtbase + rt;            // uniform
        if (R == 0) {                         // -> ft at perm_ft rows, * log2e
            float bv = bcat[l15];
            const int s0 = perm_ft(pxl);      // r only touches bits 0,1
            unsigned int p01 = cvtpk((acc[rt][0] + bv)*L2E, (acc[rt][1] + bv)*L2E);
            unsigned int p23 = cvtpk((acc[rt][2] + bv)*L2E, (acc[rt][3] + bv)*L2E);
            unsigned short* fp0 = &ft[((size_t)b*HWN + s0)*32];
            fp0[l15]       = (unsigned short)p01;         fp0[16 + l15]  = 0;
            fp0[32 + l15]  = (unsigned short)(p01 >> 16); fp0[48 + l15]  = 0;
            fp0[64 + l15]  = (unsigned short)p23;         fp0[80 + l15]  = 0;
            fp0[96 + l15]  = (unsigned short)(p23 >> 16); fp0[112 + l15] = 0;
        } else if (R == 1) {                  // -> g (4 consecutive px: uint2)
            float bv = bcat[16 + l15];
            unsigned int a01 = cvtpk(acc[rt][0] + bv, acc[rt][1] + bv);
            unsigned int a23 = cvtpk(acc[rt][2] + bv, acc[rt][3] + bv);
            *(uint2*)&g[(size_t)(b*DQK + l15)*HWN + pxl] = make_uint2(a01, a23);
        } else {                              // -> h3 frag layout
            float bv = bcat[R*16 + l15];
            unsigned int u0 = cvtpk(acc[rt][0] + bv, acc[rt][1] + bv);
            unsigned int u1 = cvtpk(acc[rt][2] + bv, acc[rt][3] + bv);
            *(uint2*)&h3[(((size_t)((b*128 + mt)*16 + (R-2))) << 9) + sub] = make_uint2(u0, u1);
        }
    }
}

// ---------------- kernel 3: MFMA flash attention, 8 waves ----------------
// Block = 512 thr, (batch, 64-q tile), grid 512. R4-proven dataflow
// (R6 lesson: swapping 4 LDS reads for 4 extra L2 loads pushed L2->CU
// traffic to ~23 TB/s and regressed; h3/ft L2 bandwidth is the scarce
// resource, LDS has headroom -> keep 8 pB reads + 4 hr loads per iter).
// R7 levers, both latency-only: (1) lgkm-only barrier (no vmcnt drain);
// (2) hr prefetch ISSUED PRE-BARRIER (consumed next iter's PV -> in-flight
// window ~barrier+S^T+PV, fully covers L2 latency). Register-neutral.
// R3 lesson: watch WRITE_SIZE ~32.8 MB for spill.
__global__ __launch_bounds__(512, 4) void attn_kernel(
    const unsigned short* __restrict__ ft, const unsigned short* __restrict__ g,
    const unsigned short* __restrict__ h3, const float* __restrict__ x,
    const float* __restrict__ gamma_p, float* __restrict__ out)
{
    const int t    = threadIdx.x;
    const int b    = blockIdx.x & 7;          // batch -> XCD pin
    const int q0   = (blockIdx.x >> 3) * 64;
    const int lane = t & 63, w = t >> 6, l15 = lane & 15, quad = lane >> 4;
    const int qt_w = w >> 1, half = w & 1;

    __shared__ __align__(16) uint4 pB[2][2][4][64];   // [buf][half][qt][lane] 16 KB
    __shared__ float l_l[4][16][2];

    union { short8 v; unsigned short u[8]; } gfrag;   // B[k=quad*8+j][q=l15] of q-tile qt_w
    #pragma unroll
    for (int j = 0; j < 8; j++) {
        int k = quad*8 + j;
        gfrag.u[j] = (k < DQK) ? g[(size_t)(b*DQK + k)*HWN + q0 + qt_w*16 + l15] : (unsigned short)0;
    }

    const unsigned short* ftb = ft + (size_t)b*HWN*32;
    const unsigned short* h3b = h3 + ((size_t)b << 20);

    short8 fr[2][2], hr[2][2][2];
    float4v acc[2][4];
    #pragma unroll
    for (int i = 0; i < 2; i++)
        #pragma unroll
        for (int j = 0; j < 4; j++) acc[i][j] = (float4v){0.f,0.f,0.f,0.f};
    float l_acc = 0.f;
    uint4 P;

    // ---- prologue: fr tile0 -> slot0, S^T(0)+exp2 -> P, fr tile1 -> slot1,
    //      hr tile0 -> slot0 ----
    #pragma unroll
    for (int j = 0; j < 2; j++)
        fr[0][j] = *(const short8*)&ftb[(size_t)((half*2 + j)*16 + l15)*32 + quad*8];
    {
        float4v z = {0.f,0.f,0.f,0.f};
        float4v s0v = __builtin_amdgcn_mfma_f32_16x16x32_bf16(fr[0][0], gfrag.v, z, 0, 0, 0);
        float4v s1v = __builtin_amdgcn_mfma_f32_16x16x32_bf16(fr[0][1], gfrag.v, z, 0, 0, 0);
        float e0 = ex2(s0v[0]), e1 = ex2(s0v[1]), e2 = ex2(s0v[2]), e3 = ex2(s0v[3]);
        float e4 = ex2(s1v[0]), e5 = ex2(s1v[1]), e6 = ex2(s1v[2]), e7 = ex2(s1v[3]);
        l_acc += (e0 + e1) + (e2 + e3) + (e4 + e5) + (e6 + e7);
        P = make_uint4(cvtpk(e0, e1), cvtpk(e2, e3), cvtpk(e4, e5), cvtpk(e6, e7));
    }
    #pragma unroll
    for (int j = 0; j < 2; j++)
        fr[1][j] = *(const short8*)&ftb[(size_t)(64 + (half*2 + j)*16 + l15)*32 + quad*8];
    #pragma unroll
    for (int grp = 0; grp < 2; grp++)
        #pragma unroll
        for (int ctl = 0; ctl < 2; ctl++)
            hr[0][grp][ctl] = *(const short8*)&h3b[(((size_t)(grp*16 + w*2 + ctl)) << 9) + lane*8];

    // Per-iter i (buf u=i&1):
    //  1. hr prefetch tile i+1 -> hr[u^1]  (PRE-barrier; consumed in iter
    //     i+1's PV; same-wave WAR vs PV(i-1)'s read of hr[u^1] is
    //     program-order-safe)
    //  2. pB[u] write of P(i)  3. lgkm-barrier
    //  4. fr prefetch tile i+2 -> fr[u] (no wrap: slop reads stay in ws)
    //  5. S^T(i+1) from fr[u^1] + exp2 -> P
    //  6. PV(i) from hr[u], pB[u] under setprio(1)
    // pB[u] WAR-safe: last readers (iter i-2) consumed pre-barrier(i-1).
#define ATTN_STEP(u, i, DO_NEXT) do {                                          \
    if (DO_NEXT) {                                                             \
      const int nh = (i) + 1;                                                  \
      _Pragma("unroll")                                                        \
      for (int grp = 0; grp < 2; grp++)                                        \
        _Pragma("unroll")                                                      \
        for (int ctl = 0; ctl < 2; ctl++)                                      \
          hr[(u)^1][grp][ctl] = *(const short8*)&h3b[(((size_t)((nh*2 + grp)*16 + w*2 + ctl)) << 9) + lane*8]; \
    }                                                                          \
    pB[u][half][qt_w][lane] = P;                                               \
    lds_barrier();                                                             \
    if (DO_NEXT) {                                                             \
      const int nf = (i) + 2;                                                  \
      _Pragma("unroll")                                                        \
      for (int j = 0; j < 2; j++)                                              \
        fr[u][j] = *(const short8*)&ftb[(size_t)(nf*64 + (half*2 + j)*16 + l15)*32 + quad*8]; \
      float4v z = {0.f,0.f,0.f,0.f};                                           \
      float4v s0v = __builtin_amdgcn_mfma_f32_16x16x32_bf16(fr[(u)^1][0], gfrag.v, z, 0, 0, 0); \
      float4v s1v = __builtin_amdgcn_mfma_f32_16x16x32_bf16(fr[(u)^1][1], gfrag.v, z, 0, 0, 0); \
      float e0 = ex2(s0v[0]), e1 = ex2(s0v[1]), e2 = ex2(s0v[2]), e3 = ex2(s0v[3]); \
      float e4 = ex2(s1v[0]), e5 = ex2(s1v[1]), e6 = ex2(s1v[2]), e7 = ex2(s1v[3]); \
      l_acc += (e0 + e1) + (e2 + e3) + (e4 + e5) + (e6 + e7);                  \
      P = make_uint4(cvtpk(e0, e1), cvtpk(e2, e3), cvtpk(e4, e5), cvtpk(e6, e7)); \
    }                                                                          \
    __builtin_amdgcn_s_setprio(1);                                             \
    _Pragma("unroll")                                                          \
    for (int grp = 0; grp < 2; grp++) {                                        \
      _Pragma("unroll")                                                        \
      for (int qt = 0; qt < 4; qt++) {                                         \
        union { uint4 uu; short8 v; } bq;                                      \
        bq.uu = pB[u][grp][qt][lane];                                          \
        _Pragma("unroll")                                                      \
        for (int ctl = 0; ctl < 2; ctl++)                                      \
          acc[ctl][qt] = __builtin_amdgcn_mfma_f32_16x16x32_bf16(hr[u][grp][ctl], bq.v, acc[ctl][qt], 0, 0, 0); \
      }                                                                        \
    }                                                                          \
    __builtin_amdgcn_s_setprio(0);                                             \
  } while (0)

    for (int i0 = 0; i0 < 62; i0 += 2) {
        ATTN_STEP(0, i0, 1);
        ATTN_STEP(1, i0 + 1, 1);
    }
    ATTN_STEP(0, 62, 1);   // computes S^T(63)+P; fr prefetch (tile 64) is dead slop
    ATTN_STEP(1, 63, 0);   // peeled tail: write P(63), PV(63) only
#undef ATTN_STEP

    // ---- l: reduce over quads; combine halves via LDS ----
    l_acc += __shfl_xor(l_acc, 16, 64);
    l_acc += __shfl_xor(l_acc, 32, 64);
    if (quad == 0) l_l[qt_w][l15][half] = l_acc;
    __syncthreads();

    const float gamma = *gamma_p;
    float linv[4];
    #pragma unroll
    for (int qt = 0; qt < 4; qt++) linv[qt] = 1.f / (l_l[qt][l15][0] + l_l[qt][l15][1]);
    #pragma unroll
    for (int ctl = 0; ctl < 2; ctl++) {
        #pragma unroll
        for (int r = 0; r < 4; r++) {
            int c = w*32 + ctl*16 + quad*4 + r;
            size_t base = (size_t)(b*CH + c)*HWN + q0;
            #pragma unroll
            for (int qt = 0; qt < 4; qt++) {
                size_t o = base + qt*16 + l15;
                out[o] = gamma * acc[ctl][qt][r] * linv[qt] + x[o];
            }
        }
    }
}

extern "C" void kernel_launch(void* const* d_in, const int* in_sizes, int n_in,
                              void* d_out, int out_size, void* d_ws, size_t ws_size,
                              hipStream_t stream) {
    const float* x     = (const float*)d_in[0];
    const float* Wf    = (const float*)d_in[1];
    const float* bf_   = (const float*)d_in[2];
    const float* Wg    = (const float*)d_in[3];
    const float* bg    = (const float*)d_in[4];
    const float* Wh    = (const float*)d_in[5];
    const float* bh    = (const float*)d_in[6];
    const float* gamma = (const float*)d_in[7];
    float* out = (float*)d_out;

    // ws: xt 16.8MB | ft 2MB | g 1MB | h3 16.8MB | Wbf 147KB | bcat
    unsigned short* xt   = (unsigned short*)d_ws;
    unsigned short* ftp  = xt  + (size_t)BATCH*HWN*CH;
    unsigned short* g    = ftp + (size_t)BATCH*HWN*32;
    unsigned short* h3   = g   + (size_t)BATCH*DQK*HWN;
    unsigned short* Wbf  = h3  + (size_t)BATCH*128*16*512;
    float*          bcat = (float*)(Wbf + 288*CH);

    wcast_kernel<<<dim3(288), 256, 0, stream>>>(Wf, bf_, Wg, bg, Wh, bh, Wbf, bcat);
    xt_kernel<<<dim3(HWN/64, CH/64, BATCH), 256, 0, stream>>>(x, xt);
    proj_kernel<<<dim3(HWN/64, BATCH, 3), 256, 0, stream>>>(xt, Wbf, bcat, ftp, g, h3);
    attn_kernel<<<dim3((HWN/64)*BATCH), 512, 0, stream>>>(ftp, g, h3, x, gamma, out);
}